// Round 1
// baseline (224.476 us; speedup 1.0000x reference)
//
#include <hip/hip_runtime.h>
#include <hip/hip_cooperative_groups.h>

namespace cg = cooperative_groups;

// B=8, C=64, H=W=64, CI=32, N=4096 pixels, M=1024 pooled.
// y[b,n,:] = (a_n*S1[k_n,:] + S2[k_n,:])/1024 ; only W_w . y is needed, so
// track U = Ww.psi (64-dim) and its sorted-order prefixes T1/T2 directly.
// BN stats from per-k scalars (cnt, sum a, sum a^2) x T rows - no Gram.
//
// r6: SINGLE COOPERATIVE KERNEL. Bottom-up cost model says the 4 phases are
// worth ~20us of real work but the 4-dispatch pipeline measures ~131us ->
// dispatch/ramp overhead dominates. Fuse all phases into one kernel with
// grid.sync() between them (3 syncs replace 3 dispatch boundaries).
// Also fused: theta a[b,n] into the phi/psi conv loop (kills the second
// full 8MB read of x and the 128-block tail). Arithmetic is kept
// bitwise-identical per element: P2 counts are integer-exact, P3 keeps the
// exact kPS structure (blocks 0..63 active), P4 expression unchanged.
#define OFF_A    0         // a[b][n]               : 32768 floats
#define OFF_BB   32768     // bb[b][m]              : 8192
#define OFF_SBB  40960     // sorted-desc bb[b][k]  : 8192
#define OFF_PERM 49152     // perm[b][k] (int)      : 8192
#define OFF_U    57344     // U[b][m][o]            : 8*1024*64 = 524288
#define OFF_T1   581632    // T1[b][k<=1024][o]     : 8*1025*64 = 524800
#define OFF_T2   1106432   // T2[b][k][o]           : 524800
#define OFF_KK   1631232   // k[b][n] (int)         : 32768
#define OFF_M    1664000   // M1[64], M2[64]        : 128
#define OFF_HC   1664128   // hist cnt[b][1025]     : 8200
#define OFF_HS   1672328   // hist sum_a[b][1025]   : 8200
#define OFF_HS2  1680528   // hist sum_a2[b][1025]  : 8200
// total 1688728 floats ~ 6.76 MB of d_ws

// LDS carve (floats), phases reuse one 8640-float block (34.6 KB):
// P1: sm[0..4160) sth[4160..4228) spsi[4228..5284) sWw[5284..7396)
// P2: sb[0..1024)
// P3: ssort[0..1024) sperm[1024..2048) shc[2048..3076) shs[3076..4104)
//     shs2[4104..5132) swp1[5132..5260) swp2[5260..5388)
// P4: tile[0..8256)=64x129 sa[8256..8384) sk[8384..8512) sA[8512..8576)
//     sD[8576..8640)
__global__ __launch_bounds__(1024) void kMega(
    const float* __restrict__ x, const float* __restrict__ theta_w,
    const float* __restrict__ theta_b, const float* __restrict__ phi_w,
    const float* __restrict__ phi_b, const float* __restrict__ psi_w,
    const float* __restrict__ psi_b, const float* __restrict__ cp_w,
    const float* __restrict__ Ww, const float* __restrict__ Wb,
    const float* __restrict__ gamma, const float* __restrict__ beta,
    float* __restrict__ ws, float* __restrict__ out)
{
    __shared__ float sh[8640];
    cg::grid_group grid = cg::this_grid();
    const int tid = threadIdx.x;
    const int bid = blockIdx.x;
    const int b   = bid >> 5;     // 32 blocks per batch image
    const int sub = bid & 31;

    // ---------- Phase 1: phi/psi conv+pool -> bb, U ; theta -> a ----------
    {
        float* sm   = sh;          // 32 i-rows x 130: interleaved {phi,psi}
        float* sth  = sh + 4160;   // tw_eff[64] + tb_eff
        float* spsi = sh + 4228;   // 32 m-rows x 32 i (pad 33)
        float* sWw  = sh + 5284;   // 64 o-rows x 32 i (pad 33)
        for (int e = tid; e < 2048; e += 1024) {
            int i = e >> 6, c = e & 63;
            sm[i*130 + 2*c]     = phi_w[e];
            sm[i*130 + 2*c + 1] = psi_w[e];
        }
        for (int e = tid; e < 2048; e += 1024)
            sWw[(e >> 5)*33 + (e & 31)] = Ww[(e >> 5)*33 + (e & 31)];
        if (tid < 64) {
            float s = 0;
            for (int i = 0; i < 32; ++i) s += cp_w[i]*theta_w[i*64 + tid];
            sth[tid] = s;
        } else if (tid == 64) {
            float s = 0;
            for (int i = 0; i < 32; ++i) s += cp_w[i]*theta_b[i];
            sth[64] = s;
        }
        if (bid == 0) {   // zero M + hist before P2/P3 atomics (pre-sync)
            for (int e = tid; e < 24728; e += 1024) ws[OFF_M + e] = 0.0f;
        }
        __syncthreads();
        int i = tid & 31;
        int mIdx = tid >> 5;                 // 0..31
        int m = (sub << 5) + mIdx;
        int ph = m >> 5, pw = m & 31;
        const float* xb = x + b*262144 + ph*128 + pw*2;
        const float2* wrow = (const float2*)(sm + i*130);
        float tb = sth[64];
        float p0=0,p1=0,p2=0,p3=0,s0=0,s1=0,s2=0,s3=0;
        float a0=tb,a1=tb,a2=tb,a3=tb;       // theta: bias-first like before
        #pragma unroll 8
        for (int c = 0; c < 64; ++c) {
            float2 xa = *(const float2*)(xb + c*4096);
            float2 xc = *(const float2*)(xb + c*4096 + 64);
            float2 w  = wrow[c];             // {phi_w, psi_w}
            float st  = sth[c];              // broadcast read
            p0 += xa.x*w.x; p1 += xa.y*w.x; p2 += xc.x*w.x; p3 += xc.y*w.x;
            s0 += xa.x*w.y; s1 += xa.y*w.y; s2 += xc.x*w.y; s3 += xc.y*w.y;
            a0 += xa.x*st;  a1 += xa.y*st;  a2 += xc.x*st;  a3 += xc.y*st;
        }
        float pv = fmaxf(fmaxf(p0,p1), fmaxf(p2,p3)) + phi_b[i];
        float sv = fmaxf(fmaxf(s0,s1), fmaxf(s2,s3)) + psi_b[i];
        spsi[mIdx*33 + i] = sv;
        float v = pv * cp_w[32 + i];
        v += __shfl_xor(v, 16, 32);
        v += __shfl_xor(v,  8, 32);
        v += __shfl_xor(v,  4, 32);
        v += __shfl_xor(v,  2, 32);
        v += __shfl_xor(v,  1, 32);
        if (i == 0) {
            ws[OFF_BB + (b<<10) + m] = v;
            int nb = (b<<12) + ph*128 + pw*2;   // pixel (2ph,2pw)
            ws[OFF_A + nb]      = a0;
            ws[OFF_A + nb + 1]  = a1;
            ws[OFF_A + nb + 64] = a2;
            ws[OFF_A + nb + 65] = a3;
        }
        __syncthreads();
        #pragma unroll
        for (int rep = 0; rep < 2; ++rep) {
            int idx = tid + (rep << 10);     // 2048 outputs = 32 m x 64 o
            int ml = idx >> 6, o = idx & 63;
            const float* pr = &spsi[ml*33];  // wave-uniform ml: broadcast
            const float* wr = &sWw[o*33];    // (o+i)%32: 2-way max (free)
            float u = 0;
            #pragma unroll
            for (int i2 = 0; i2 < 32; ++i2) u += pr[i2]*wr[i2];
            ws[OFF_U + (((b<<10) + (sub<<5) + ml) << 6) + o] = u;
        }
    }
    grid.sync();

    // ---------- Phase 2: rank bb, k_n per pixel, per-b histogram ----------
    {
        float* sb = sh;
        sb[tid] = ws[OFF_BB + (b<<10) + tid];
        __syncthreads();
        {   // rank 32 m's of this chunk (32 lanes per m, integer-exact)
            int ml = tid >> 5, jl = tid & 31;
            int m = (sub << 5) + ml;
            float vv = sb[m];
            int cnt = 0;
            for (int s = 0; s < 32; ++s) {
                int j = jl + (s << 5);
                float u = sb[j];
                cnt += (u > vv || (u == vv && j < m)) ? 1 : 0;
            }
            cnt += __shfl_xor(cnt,  1, 32);
            cnt += __shfl_xor(cnt,  2, 32);
            cnt += __shfl_xor(cnt,  4, 32);
            cnt += __shfl_xor(cnt,  8, 32);
            cnt += __shfl_xor(cnt, 16, 32);
            if (jl == 0) {
                ws[OFF_SBB + (b<<10) + cnt] = vv;
                ((int*)ws)[OFF_PERM + (b<<10) + cnt] = m;
            }
        }
        {   // k_n for 128 pixels (8 lanes per pixel) + hist atomics
            int l = tid >> 3, jl = tid & 7;
            int n = (sub << 7) + l;
            float av = ws[OFF_A + (b<<12) + n];
            float tt = -av;
            const float2* sb2 = (const float2*)sb;
            int cnt = 0;
            for (int s = 0; s < 64; ++s) {
                float2 u = sb2[jl + (s << 3)];  // 8 distinct addrs: free
                cnt += (u.x > tt) ? 1 : 0;
                cnt += (u.y > tt) ? 1 : 0;
            }
            cnt += __shfl_xor(cnt, 1, 8);
            cnt += __shfl_xor(cnt, 2, 8);
            cnt += __shfl_xor(cnt, 4, 8);
            if (jl == 0) {
                ((int*)ws)[OFF_KK + (b<<12) + n] = cnt;
                atomicAdd(&ws[OFF_HC + b*1025 + cnt], 1.0f);
                atomicAdd(&ws[OFF_HS + b*1025 + cnt], av);
                atomicAdd(&ws[OFF_HS2 + b*1025 + cnt], av*av);
            }
        }
    }
    grid.sync();

    // ---------- Phase 3: sorted prefixes T1/T2 + BN moment partials ------
    // Exact kPS structure (bitwise-identical T1/T2); blocks 0..63 active.
    if (bid < 64) {
        int b3 = bid >> 3, og = bid & 7;
        int obase = og << 3;
        float* ssort = sh;
        int*   sperm = (int*)(sh + 1024);
        float* shc   = sh + 2048;
        float* shs   = sh + 3076;
        float* shs2  = sh + 4104;
        float* swp1  = sh + 5132;
        float* swp2  = sh + 5260;
        ssort[tid] = ws[OFF_SBB + (b3<<10) + tid];
        sperm[tid] = ((const int*)ws)[OFF_PERM + (b3<<10) + tid];
        shc[tid]  = ws[OFF_HC  + b3*1025 + tid];
        shs[tid]  = ws[OFF_HS  + b3*1025 + tid];
        shs2[tid] = ws[OFF_HS2 + b3*1025 + tid];
        if (tid == 0) {
            shc[1024]  = ws[OFF_HC  + b3*1025 + 1024];
            shs[1024]  = ws[OFF_HS  + b3*1025 + 1024];
            shs2[1024] = ws[OFF_HS2 + b3*1025 + 1024];
        }
        __syncthreads();
        int ch = tid >> 3, o = tid & 7;
        int wv = tid >> 6, chl = (tid & 63) >> 3;   // ch = wv*8 + chl
        const float* Ub = ws + OFF_U + (b3<<16) + obase + o;
        float p[8], sp[8];
        float s1 = 0, s2 = 0;
        #pragma unroll
        for (int jl = 0; jl < 8; ++jl) {
            int jj = (ch<<3) + jl;
            float v = Ub[sperm[jj]<<6];
            p[jl] = v;
            sp[jl] = ssort[jj]*v;
            s1 += v; s2 += sp[jl];
        }
        float own1 = s1, own2 = s2;
        #pragma unroll
        for (int d = 1; d < 8; d <<= 1) {
            float u1 = __shfl_up(s1, d<<3, 64);
            float u2 = __shfl_up(s2, d<<3, 64);
            if (chl >= d) { s1 += u1; s2 += u2; }
        }
        if (chl == 7) { swp1[(wv<<3)+o] = s1; swp2[(wv<<3)+o] = s2; }
        __syncthreads();
        float off1 = 0, off2 = 0;
        for (int w = 0; w < 16; ++w) {
            if (w < wv) { off1 += swp1[(w<<3)+o]; off2 += swp2[(w<<3)+o]; }
        }
        float run1 = off1 + s1 - own1;   // exclusive prefix before chunk ch
        float run2 = off2 + s2 - own2;
        float* T1 = ws + OFF_T1 + b3*65600 + obase + o;
        float* T2 = ws + OFF_T2 + b3*65600 + obase + o;
        if (ch == 0) { T1[0] = 0.0f; T2[0] = 0.0f; }   // k=0 row
        const float inv = 1.0f/1024.0f;
        float m1 = 0, m2 = 0;
        #pragma unroll
        for (int jl = 0; jl < 8; ++jl) {
            int k = (ch<<3) + jl + 1;
            run1 += p[jl]; run2 += sp[jl];
            float t1 = run1*inv, t2 = run2*inv;
            T1[k<<6] = t1;
            T2[k<<6] = t2;
            float c = shc[k], sa_ = shs[k], sa2 = shs2[k];
            m1 += sa_*t1 + c*t2;
            m2 += (sa2*t1 + 2.0f*sa_*t2)*t1 + c*t2*t2;
        }
        m1 += __shfl_xor(m1,  8, 64); m2 += __shfl_xor(m2,  8, 64);
        m1 += __shfl_xor(m1, 16, 64); m2 += __shfl_xor(m2, 16, 64);
        m1 += __shfl_xor(m1, 32, 64); m2 += __shfl_xor(m2, 32, 64);
        __syncthreads();   // swp reuse
        if (chl == 0) { swp1[(wv<<3)+o] = m1; swp2[(wv<<3)+o] = m2; }
        __syncthreads();
        if (tid < 8) {
            float a1 = 0, a2 = 0;
            for (int w = 0; w < 16; ++w) {
                a1 += swp1[(w<<3)+tid]; a2 += swp2[(w<<3)+tid];
            }
            atomicAdd(&ws[OFF_M + obase + tid], a1);
            atomicAdd(&ws[OFF_M + 64 + obase + tid], a2);
        }
    }
    grid.sync();

    // ---------- Phase 4: output tile (128 pixels per block) --------------
    {
        float* tile = sh;               // 64 o x 129 (pad)
        float* sa = sh + 8256;          // a for 128 pixels
        int*   sk = (int*)(sh + 8384);  // k for 128 pixels
        float* sA = sh + 8512;
        float* sD = sh + 8576;
        int n0 = sub << 7;
        if (tid < 128) {
            sa[tid] = ws[OFF_A + (b<<12) + n0 + tid];
            sk[tid] = ((const int*)ws)[OFF_KK + (b<<12) + n0 + tid];
        }
        if (tid < 64) {
            const float Ninv = 1.0f/32768.0f;
            float m1 = ws[OFF_M + tid] * Ninv;
            float m2 = ws[OFF_M + 64 + tid] * Ninv;
            float wb = Wb[tid];
            float mu  = m1 + wb;
            float E2  = m2 + 2.0f*wb*m1 + wb*wb;
            float var = E2 - mu*mu;
            float A = gamma[tid] * rsqrtf(var + 1e-5f);
            sA[tid] = A;
            sD[tid] = beta[tid] + A*(wb - mu);
        }
        __syncthreads();
        const float* T1 = ws + OFF_T1 + b*65600;
        const float* T2 = ws + OFF_T2 + b*65600;
        {
            int o = tid & 63, ng = tid >> 6;   // 16 groups x 8 n
            float Ao = sA[o], Do = sD[o];
            #pragma unroll
            for (int j = 0; j < 8; ++j) {
                int n = (ng << 3) + j;
                int k = sk[n];                 // wave-uniform -> T coalesced
                float a = sa[n];
                float t1 = T1[(k<<6) + o];
                float t2 = T2[(k<<6) + o];
                tile[o*129 + n] = Ao*(a*t1 + t2) + Do;
            }
        }
        __syncthreads();
        {
            int n = tid & 127, og = tid >> 7;  // 8 groups x 8 o
            #pragma unroll
            for (int j = 0; j < 8; ++j) {
                int o = (og << 3) + j;
                int idx = ((b<<6) + o)*4096 + n0 + n;
                out[idx] = tile[o*129 + n] + x[idx];
            }
        }
    }
}

extern "C" void kernel_launch(void* const* d_in, const int* in_sizes, int n_in,
                              void* d_out, int out_size, void* d_ws, size_t ws_size,
                              hipStream_t stream)
{
    const float* x       = (const float*)d_in[0];
    const float* theta_w = (const float*)d_in[1];
    const float* theta_b = (const float*)d_in[2];
    const float* phi_w   = (const float*)d_in[3];
    const float* phi_b   = (const float*)d_in[4];
    const float* psi_w   = (const float*)d_in[5];
    const float* psi_b   = (const float*)d_in[6];
    const float* cp_w    = (const float*)d_in[7];
    const float* Ww      = (const float*)d_in[8];
    const float* Wb      = (const float*)d_in[9];
    const float* gamma   = (const float*)d_in[10];
    const float* beta    = (const float*)d_in[11];
    float* ws  = (float*)d_ws;
    float* out = (float*)d_out;

    void* args[] = { (void*)&x, (void*)&theta_w, (void*)&theta_b,
                     (void*)&phi_w, (void*)&phi_b, (void*)&psi_w,
                     (void*)&psi_b, (void*)&cp_w, (void*)&Ww, (void*)&Wb,
                     (void*)&gamma, (void*)&beta, (void*)&ws, (void*)&out };
    hipLaunchCooperativeKernel((const void*)kMega, dim3(256), dim3(1024),
                               args, 0, stream);
}

// Round 2
// 185.841 us; speedup vs baseline: 1.2079x; 1.2079x over previous
//
#include <hip/hip_runtime.h>

// B=8, C=64, H=W=64, CI=32, N=4096 pixels, M=1024 pooled.
// y[b,n,:] = (a_n*S1[k_n,:] + S2[k_n,:])/1024 ; only W_w . y is needed, so
// track U = Ww.psi (64-dim) and its sorted-order prefixes T1/T2 directly.
// BN stats from per-k scalars (cnt, sum a, sum a^2) x T rows - no Gram.
//
// r7: fused kernel kept (r6 showed the 4 phases total ~124us in one
// dispatch) but cooperative launch DROPPED: hipLaunchCooperativeKernel cost
// ~100us/iter (224 end-to-end vs 124 kernel), and cg::grid.sync() is the
// ~90us in-kernel mystery (VALUBusy 8%, HBM 3%, occupancy 46% -> all pipes
// idle -> spinning in sync). Replaced with a hand-rolled monotonic-counter
// barrier. Residency proof for normal launch: 36 VGPR / 34.6KB LDS ->
// 2 blocks/CU capacity, 512 slots >= 256 blocks -> all blocks resident
// regardless of packing; no deadlock. M/hist/barrier zeroing moved to one
// hipMemsetAsync (graph-capturable, the harness itself enqueues fills).
#define OFF_A    0         // a[b][n]               : 32768 floats
#define OFF_BB   32768     // bb[b][m]              : 8192
#define OFF_SBB  40960     // sorted-desc bb[b][k]  : 8192
#define OFF_PERM 49152     // perm[b][k] (int)      : 8192
#define OFF_U    57344     // U[b][m][o]            : 8*1024*64 = 524288
#define OFF_T1   581632    // T1[b][k<=1024][o]     : 8*1025*64 = 524800
#define OFF_T2   1106432   // T2[b][k][o]           : 524800
#define OFF_KK   1631232   // k[b][n] (int)         : 32768
#define OFF_M    1664000   // M1[64], M2[64]        : 128
#define OFF_HC   1664128   // hist cnt[b][1025]     : 8200
#define OFF_HS   1672328   // hist sum_a[b][1025]   : 8200
#define OFF_HS2  1680528   // hist sum_a2[b][1025]  : 8200
#define OFF_BAR  1688728   // barrier counter (1 uint) + pad
// memset zeroes floats [OFF_M, OFF_BAR+4) = 24732 floats = 98928 bytes

#define NBLK 256

// Monotonic grid barrier: every block arrives (atomicAdd), thread 0 spins
// until all NBLK arrivals of this generation are in. Counter is zeroed by
// the pre-kernel memset each iteration; goals are gen*NBLK (no reset race).
__device__ __forceinline__ void gbar(float* ws, unsigned goal)
{
    __syncthreads();
    if (threadIdx.x == 0) {
        unsigned* bar = (unsigned*)(ws + OFF_BAR);
        __threadfence();   // release: make this block's writes visible
        __hip_atomic_fetch_add(bar, 1u, __ATOMIC_RELEASE,
                               __HIP_MEMORY_SCOPE_AGENT);
        while (__hip_atomic_load(bar, __ATOMIC_RELAXED,
                                 __HIP_MEMORY_SCOPE_AGENT) < goal)
            __builtin_amdgcn_s_sleep(2);
        __threadfence();   // acquire: invalidate stale cached lines
    }
    __syncthreads();
}

// LDS carve (floats), phases reuse one 8640-float block (34.6 KB):
// P1: sm[0..4160) sth[4160..4228) spsi[4228..5284) sWw[5284..7396)
// P2: sb[0..1024)
// P3: ssort[0..1024) sperm[1024..2048) shc[2048..3076) shs[3076..4104)
//     shs2[4104..5132) swp1[5132..5260) swp2[5260..5388)
// P4: tile[0..8256)=64x129 sa[8256..8384) sk[8384..8512) sA[8512..8576)
//     sD[8576..8640)
__global__ __launch_bounds__(1024) void kMega(
    const float* __restrict__ x, const float* __restrict__ theta_w,
    const float* __restrict__ theta_b, const float* __restrict__ phi_w,
    const float* __restrict__ phi_b, const float* __restrict__ psi_w,
    const float* __restrict__ psi_b, const float* __restrict__ cp_w,
    const float* __restrict__ Ww, const float* __restrict__ Wb,
    const float* __restrict__ gamma, const float* __restrict__ beta,
    float* __restrict__ ws, float* __restrict__ out)
{
    __shared__ float sh[8640];
    const int tid = threadIdx.x;
    const int bid = blockIdx.x;
    const int b   = bid >> 5;     // 32 blocks per batch image
    const int sub = bid & 31;

    // ---------- Phase 1: phi/psi conv+pool -> bb, U ; theta -> a ----------
    {
        float* sm   = sh;          // 32 i-rows x 130: interleaved {phi,psi}
        float* sth  = sh + 4160;   // tw_eff[64] + tb_eff
        float* spsi = sh + 4228;   // 32 m-rows x 32 i (pad 33)
        float* sWw  = sh + 5284;   // 64 o-rows x 32 i (pad 33)
        for (int e = tid; e < 2048; e += 1024) {
            int i = e >> 6, c = e & 63;
            sm[i*130 + 2*c]     = phi_w[e];
            sm[i*130 + 2*c + 1] = psi_w[e];
        }
        for (int e = tid; e < 2048; e += 1024)
            sWw[(e >> 5)*33 + (e & 31)] = Ww[(e >> 5)*33 + (e & 31)];
        if (tid < 64) {
            float s = 0;
            for (int i = 0; i < 32; ++i) s += cp_w[i]*theta_w[i*64 + tid];
            sth[tid] = s;
        } else if (tid == 64) {
            float s = 0;
            for (int i = 0; i < 32; ++i) s += cp_w[i]*theta_b[i];
            sth[64] = s;
        }
        __syncthreads();
        int i = tid & 31;
        int mIdx = tid >> 5;                 // 0..31
        int m = (sub << 5) + mIdx;
        int ph = m >> 5, pw = m & 31;
        const float* xb = x + b*262144 + ph*128 + pw*2;
        const float2* wrow = (const float2*)(sm + i*130);
        float tb = sth[64];
        float p0=0,p1=0,p2=0,p3=0,s0=0,s1=0,s2=0,s3=0;
        float a0=tb,a1=tb,a2=tb,a3=tb;       // theta: bias-first like before
        #pragma unroll 8
        for (int c = 0; c < 64; ++c) {
            float2 xa = *(const float2*)(xb + c*4096);
            float2 xc = *(const float2*)(xb + c*4096 + 64);
            float2 w  = wrow[c];             // {phi_w, psi_w}
            float st  = sth[c];              // broadcast read
            p0 += xa.x*w.x; p1 += xa.y*w.x; p2 += xc.x*w.x; p3 += xc.y*w.x;
            s0 += xa.x*w.y; s1 += xa.y*w.y; s2 += xc.x*w.y; s3 += xc.y*w.y;
            a0 += xa.x*st;  a1 += xa.y*st;  a2 += xc.x*st;  a3 += xc.y*st;
        }
        float pv = fmaxf(fmaxf(p0,p1), fmaxf(p2,p3)) + phi_b[i];
        float sv = fmaxf(fmaxf(s0,s1), fmaxf(s2,s3)) + psi_b[i];
        spsi[mIdx*33 + i] = sv;
        float v = pv * cp_w[32 + i];
        v += __shfl_xor(v, 16, 32);
        v += __shfl_xor(v,  8, 32);
        v += __shfl_xor(v,  4, 32);
        v += __shfl_xor(v,  2, 32);
        v += __shfl_xor(v,  1, 32);
        if (i == 0) {
            ws[OFF_BB + (b<<10) + m] = v;
            int nb = (b<<12) + ph*128 + pw*2;   // pixel (2ph,2pw)
            ws[OFF_A + nb]      = a0;
            ws[OFF_A + nb + 1]  = a1;
            ws[OFF_A + nb + 64] = a2;
            ws[OFF_A + nb + 65] = a3;
        }
        __syncthreads();
        #pragma unroll
        for (int rep = 0; rep < 2; ++rep) {
            int idx = tid + (rep << 10);     // 2048 outputs = 32 m x 64 o
            int ml = idx >> 6, o = idx & 63;
            const float* pr = &spsi[ml*33];  // wave-uniform ml: broadcast
            const float* wr = &sWw[o*33];    // (o+i)%32: 2-way max (free)
            float u = 0;
            #pragma unroll
            for (int i2 = 0; i2 < 32; ++i2) u += pr[i2]*wr[i2];
            ws[OFF_U + (((b<<10) + (sub<<5) + ml) << 6) + o] = u;
        }
    }
    gbar(ws, NBLK);

    // ---------- Phase 2: rank bb, k_n per pixel, per-b histogram ----------
    {
        float* sb = sh;
        sb[tid] = ws[OFF_BB + (b<<10) + tid];
        __syncthreads();
        {   // rank 32 m's of this chunk (32 lanes per m, integer-exact)
            int ml = tid >> 5, jl = tid & 31;
            int m = (sub << 5) + ml;
            float vv = sb[m];
            int cnt = 0;
            for (int s = 0; s < 32; ++s) {
                int j = jl + (s << 5);
                float u = sb[j];
                cnt += (u > vv || (u == vv && j < m)) ? 1 : 0;
            }
            cnt += __shfl_xor(cnt,  1, 32);
            cnt += __shfl_xor(cnt,  2, 32);
            cnt += __shfl_xor(cnt,  4, 32);
            cnt += __shfl_xor(cnt,  8, 32);
            cnt += __shfl_xor(cnt, 16, 32);
            if (jl == 0) {
                ws[OFF_SBB + (b<<10) + cnt] = vv;
                ((int*)ws)[OFF_PERM + (b<<10) + cnt] = m;
            }
        }
        {   // k_n for 128 pixels (8 lanes per pixel) + hist atomics
            int l = tid >> 3, jl = tid & 7;
            int n = (sub << 7) + l;
            float av = ws[OFF_A + (b<<12) + n];
            float tt = -av;
            const float2* sb2 = (const float2*)sb;
            int cnt = 0;
            for (int s = 0; s < 64; ++s) {
                float2 u = sb2[jl + (s << 3)];  // 8 distinct addrs: free
                cnt += (u.x > tt) ? 1 : 0;
                cnt += (u.y > tt) ? 1 : 0;
            }
            cnt += __shfl_xor(cnt, 1, 8);
            cnt += __shfl_xor(cnt, 2, 8);
            cnt += __shfl_xor(cnt, 4, 8);
            if (jl == 0) {
                ((int*)ws)[OFF_KK + (b<<12) + n] = cnt;
                atomicAdd(&ws[OFF_HC + b*1025 + cnt], 1.0f);
                atomicAdd(&ws[OFF_HS + b*1025 + cnt], av);
                atomicAdd(&ws[OFF_HS2 + b*1025 + cnt], av*av);
            }
        }
    }
    gbar(ws, 2*NBLK);

    // ---------- Phase 3: sorted prefixes T1/T2 + BN moment partials ------
    // Exact kPS structure (bitwise-identical T1/T2); blocks 0..63 active.
    if (bid < 64) {
        int b3 = bid >> 3, og = bid & 7;
        int obase = og << 3;
        float* ssort = sh;
        int*   sperm = (int*)(sh + 1024);
        float* shc   = sh + 2048;
        float* shs   = sh + 3076;
        float* shs2  = sh + 4104;
        float* swp1  = sh + 5132;
        float* swp2  = sh + 5260;
        ssort[tid] = ws[OFF_SBB + (b3<<10) + tid];
        sperm[tid] = ((const int*)ws)[OFF_PERM + (b3<<10) + tid];
        shc[tid]  = ws[OFF_HC  + b3*1025 + tid];
        shs[tid]  = ws[OFF_HS  + b3*1025 + tid];
        shs2[tid] = ws[OFF_HS2 + b3*1025 + tid];
        if (tid == 0) {
            shc[1024]  = ws[OFF_HC  + b3*1025 + 1024];
            shs[1024]  = ws[OFF_HS  + b3*1025 + 1024];
            shs2[1024] = ws[OFF_HS2 + b3*1025 + 1024];
        }
        __syncthreads();
        int ch = tid >> 3, o = tid & 7;
        int wv = tid >> 6, chl = (tid & 63) >> 3;   // ch = wv*8 + chl
        const float* Ub = ws + OFF_U + (b3<<16) + obase + o;
        float p[8], sp[8];
        float s1 = 0, s2 = 0;
        #pragma unroll
        for (int jl = 0; jl < 8; ++jl) {
            int jj = (ch<<3) + jl;
            float v = Ub[sperm[jj]<<6];
            p[jl] = v;
            sp[jl] = ssort[jj]*v;
            s1 += v; s2 += sp[jl];
        }
        float own1 = s1, own2 = s2;
        #pragma unroll
        for (int d = 1; d < 8; d <<= 1) {
            float u1 = __shfl_up(s1, d<<3, 64);
            float u2 = __shfl_up(s2, d<<3, 64);
            if (chl >= d) { s1 += u1; s2 += u2; }
        }
        if (chl == 7) { swp1[(wv<<3)+o] = s1; swp2[(wv<<3)+o] = s2; }
        __syncthreads();
        float off1 = 0, off2 = 0;
        for (int w = 0; w < 16; ++w) {
            if (w < wv) { off1 += swp1[(w<<3)+o]; off2 += swp2[(w<<3)+o]; }
        }
        float run1 = off1 + s1 - own1;   // exclusive prefix before chunk ch
        float run2 = off2 + s2 - own2;
        float* T1 = ws + OFF_T1 + b3*65600 + obase + o;
        float* T2 = ws + OFF_T2 + b3*65600 + obase + o;
        if (ch == 0) { T1[0] = 0.0f; T2[0] = 0.0f; }   // k=0 row
        const float inv = 1.0f/1024.0f;
        float m1 = 0, m2 = 0;
        #pragma unroll
        for (int jl = 0; jl < 8; ++jl) {
            int k = (ch<<3) + jl + 1;
            run1 += p[jl]; run2 += sp[jl];
            float t1 = run1*inv, t2 = run2*inv;
            T1[k<<6] = t1;
            T2[k<<6] = t2;
            float c = shc[k], sa_ = shs[k], sa2 = shs2[k];
            m1 += sa_*t1 + c*t2;
            m2 += (sa2*t1 + 2.0f*sa_*t2)*t1 + c*t2*t2;
        }
        m1 += __shfl_xor(m1,  8, 64); m2 += __shfl_xor(m2,  8, 64);
        m1 += __shfl_xor(m1, 16, 64); m2 += __shfl_xor(m2, 16, 64);
        m1 += __shfl_xor(m1, 32, 64); m2 += __shfl_xor(m2, 32, 64);
        __syncthreads();   // swp reuse
        if (chl == 0) { swp1[(wv<<3)+o] = m1; swp2[(wv<<3)+o] = m2; }
        __syncthreads();
        if (tid < 8) {
            float a1 = 0, a2 = 0;
            for (int w = 0; w < 16; ++w) {
                a1 += swp1[(w<<3)+tid]; a2 += swp2[(w<<3)+tid];
            }
            atomicAdd(&ws[OFF_M + obase + tid], a1);
            atomicAdd(&ws[OFF_M + 64 + obase + tid], a2);
        }
    }
    gbar(ws, 3*NBLK);

    // ---------- Phase 4: output tile (128 pixels per block) --------------
    {
        float* tile = sh;               // 64 o x 129 (pad)
        float* sa = sh + 8256;          // a for 128 pixels
        int*   sk = (int*)(sh + 8384);  // k for 128 pixels
        float* sA = sh + 8512;
        float* sD = sh + 8576;
        int n0 = sub << 7;
        if (tid < 128) {
            sa[tid] = ws[OFF_A + (b<<12) + n0 + tid];
            sk[tid] = ((const int*)ws)[OFF_KK + (b<<12) + n0 + tid];
        }
        if (tid < 64) {
            const float Ninv = 1.0f/32768.0f;
            float m1 = ws[OFF_M + tid] * Ninv;
            float m2 = ws[OFF_M + 64 + tid] * Ninv;
            float wb = Wb[tid];
            float mu  = m1 + wb;
            float E2  = m2 + 2.0f*wb*m1 + wb*wb;
            float var = E2 - mu*mu;
            float A = gamma[tid] * rsqrtf(var + 1e-5f);
            sA[tid] = A;
            sD[tid] = beta[tid] + A*(wb - mu);
        }
        __syncthreads();
        const float* T1 = ws + OFF_T1 + b*65600;
        const float* T2 = ws + OFF_T2 + b*65600;
        {
            int o = tid & 63, ng = tid >> 6;   // 16 groups x 8 n
            float Ao = sA[o], Do = sD[o];
            #pragma unroll
            for (int j = 0; j < 8; ++j) {
                int n = (ng << 3) + j;
                int k = sk[n];                 // wave-uniform -> T coalesced
                float a = sa[n];
                float t1 = T1[(k<<6) + o];
                float t2 = T2[(k<<6) + o];
                tile[o*129 + n] = Ao*(a*t1 + t2) + Do;
            }
        }
        __syncthreads();
        {
            int n = tid & 127, og = tid >> 7;  // 8 groups x 8 o
            #pragma unroll
            for (int j = 0; j < 8; ++j) {
                int o = (og << 3) + j;
                int idx = ((b<<6) + o)*4096 + n0 + n;
                out[idx] = tile[o*129 + n] + x[idx];
            }
        }
    }
}

extern "C" void kernel_launch(void* const* d_in, const int* in_sizes, int n_in,
                              void* d_out, int out_size, void* d_ws, size_t ws_size,
                              hipStream_t stream)
{
    const float* x       = (const float*)d_in[0];
    const float* theta_w = (const float*)d_in[1];
    const float* theta_b = (const float*)d_in[2];
    const float* phi_w   = (const float*)d_in[3];
    const float* phi_b   = (const float*)d_in[4];
    const float* psi_w   = (const float*)d_in[5];
    const float* psi_b   = (const float*)d_in[6];
    const float* cp_w    = (const float*)d_in[7];
    const float* Ww      = (const float*)d_in[8];
    const float* Wb      = (const float*)d_in[9];
    const float* gamma   = (const float*)d_in[10];
    const float* beta    = (const float*)d_in[11];
    float* ws  = (float*)d_ws;
    float* out = (float*)d_out;

    // Zero M + hist + barrier counter in one contiguous memset:
    // floats [OFF_M, OFF_BAR+1) = 24732 floats = 98928 bytes.
    hipMemsetAsync(ws + OFF_M, 0, 24732 * sizeof(float), stream);

    kMega<<<256, 1024, 0, stream>>>(x, theta_w, theta_b, phi_w, phi_b,
                                    psi_w, psi_b, cp_w, Ww, Wb,
                                    gamma, beta, ws, out);
}

// Round 3
// 169.194 us; speedup vs baseline: 1.3267x; 1.0984x over previous
//
#include <hip/hip_runtime.h>

// B=8, C=64, H=W=64, CI=32, N=4096 pixels, M=1024 pooled.
// y[b,n,:] = (a_n*S1[k_n,:] + S2[k_n,:])/1024 ; only W_w . y is needed, so
// track U = Ww.psi (64-dim) and its sorted-order prefixes T1/T2 directly.
// BN stats from per-k scalars (cnt, sum a, sum a^2) x T rows - no Gram.
//
// r8: barrier forensics. r7 measured: phases ~= 9.6us VALU / ~30us total,
// barriers ~75us (3 x ~25us). Common cost of grid.sync and the r7 flat
// barrier: 256 same-address device-scope atomic RMWs serializing at the
// coherence point (~100ns each cross-XCD => ~25us). Fix:
//  - two-level tree arrival: 8 group counters (128B apart, 32 arrivals
//    each, parallel across lines) + root (8 RMWs); spinners poll root
//    read-only.
//  - P3 BN-moment atomics (128 same-line RMWs) -> plain per-(b,og)
//    partial writes; P4 reduces the 8 batch partials per channel.
// Residency: 32 VGPR / 34.8KB LDS -> >=2 blocks/CU capacity, 256 blocks
// always co-resident; no deadlock.
#define OFF_A    0         // a[b][n]               : 32768 floats
#define OFF_BB   32768     // bb[b][m]              : 8192
#define OFF_SBB  40960     // sorted-desc bb[b][k]  : 8192
#define OFF_PERM 49152     // perm[b][k] (int)      : 8192
#define OFF_U    57344     // U[b][m][o]            : 8*1024*64 = 524288
#define OFF_T1   581632    // T1[b][k<=1024][o]     : 8*1025*64 = 524800
#define OFF_T2   1106432   // T2[b][k][o]           : 524800
#define OFF_KK   1631232   // k[b][n] (int)         : 32768
#define OFF_MP1  1664000   // moment1 partials [b3][o] : 512
#define OFF_MP2  1664512   // moment2 partials [b3][o] : 512
#define OFF_HC   1665024   // hist cnt[b][1025]     : 8200
#define OFF_HS   1673224   // hist sum_a[b][1025]   : 8200
#define OFF_HS2  1681424   // hist sum_a2[b][1025]  : 8200
#define OFF_BAR  1689624   // root ctr @+0; group g ctr @+32*(g+1); 288 u32
// memset zeroes floats [OFF_HC, OFF_BAR+288) = 24888 floats = 99552 bytes

#define NBLK 256
#define NGRP 8

// Two-level monotonic grid barrier. Blocks arrive at their group counter
// (8 parallel cache lines, 32 RMWs each); the last arriver of each group
// bumps the root; everyone spins on the root (read-only polls).
// Counters zeroed by the pre-kernel memset; goals are gen-scaled.
__device__ __forceinline__ void gbar(float* ws, int gen)
{
    __syncthreads();
    if (threadIdx.x == 0) {
        unsigned* bars = (unsigned*)(ws + OFF_BAR);
        unsigned* grp  = bars + ((blockIdx.x >> 5) + 1) * 32;
        __threadfence();   // release: make this block's writes visible
        unsigned old = __hip_atomic_fetch_add(grp, 1u, __ATOMIC_ACQ_REL,
                                              __HIP_MEMORY_SCOPE_AGENT);
        if (old == (unsigned)(gen * 32 - 1))     // last of this 32-group
            __hip_atomic_fetch_add(bars, 1u, __ATOMIC_ACQ_REL,
                                   __HIP_MEMORY_SCOPE_AGENT);
        unsigned goal = (unsigned)(gen * NGRP);
        while (__hip_atomic_load(bars, __ATOMIC_RELAXED,
                                 __HIP_MEMORY_SCOPE_AGENT) < goal)
            __builtin_amdgcn_s_sleep(2);
        __threadfence();   // acquire: drop stale L1/L2 lines
    }
    __syncthreads();
}

// LDS carve (floats), phases reuse one 8640-float block (34.6 KB):
// P1: sm[0..4160) sth[4160..4228) spsi[4228..5284) sWw[5284..7396)
// P2: sb[0..1024)
// P3: ssort[0..1024) sperm[1024..2048) shc[2048..3076) shs[3076..4104)
//     shs2[4104..5132) swp1[5132..5260) swp2[5260..5388)
// P4: tile[0..8256)=64x129 sa[8256..8384) sk[8384..8512) sA[8512..8576)
//     sD[8576..8640)
__global__ __launch_bounds__(1024) void kMega(
    const float* __restrict__ x, const float* __restrict__ theta_w,
    const float* __restrict__ theta_b, const float* __restrict__ phi_w,
    const float* __restrict__ phi_b, const float* __restrict__ psi_w,
    const float* __restrict__ psi_b, const float* __restrict__ cp_w,
    const float* __restrict__ Ww, const float* __restrict__ Wb,
    const float* __restrict__ gamma, const float* __restrict__ beta,
    float* __restrict__ ws, float* __restrict__ out)
{
    __shared__ float sh[8640];
    const int tid = threadIdx.x;
    const int bid = blockIdx.x;
    const int b   = bid >> 5;     // 32 blocks per batch image
    const int sub = bid & 31;

    // ---------- Phase 1: phi/psi conv+pool -> bb, U ; theta -> a ----------
    {
        float* sm   = sh;          // 32 i-rows x 130: interleaved {phi,psi}
        float* sth  = sh + 4160;   // tw_eff[64] + tb_eff
        float* spsi = sh + 4228;   // 32 m-rows x 32 i (pad 33)
        float* sWw  = sh + 5284;   // 64 o-rows x 32 i (pad 33)
        for (int e = tid; e < 2048; e += 1024) {
            int i = e >> 6, c = e & 63;
            sm[i*130 + 2*c]     = phi_w[e];
            sm[i*130 + 2*c + 1] = psi_w[e];
        }
        for (int e = tid; e < 2048; e += 1024)
            sWw[(e >> 5)*33 + (e & 31)] = Ww[(e >> 5)*33 + (e & 31)];
        if (tid < 64) {
            float s = 0;
            for (int i = 0; i < 32; ++i) s += cp_w[i]*theta_w[i*64 + tid];
            sth[tid] = s;
        } else if (tid == 64) {
            float s = 0;
            for (int i = 0; i < 32; ++i) s += cp_w[i]*theta_b[i];
            sth[64] = s;
        }
        __syncthreads();
        int i = tid & 31;
        int mIdx = tid >> 5;                 // 0..31
        int m = (sub << 5) + mIdx;
        int ph = m >> 5, pw = m & 31;
        const float* xb = x + b*262144 + ph*128 + pw*2;
        const float2* wrow = (const float2*)(sm + i*130);
        float tb = sth[64];
        float p0=0,p1=0,p2=0,p3=0,s0=0,s1=0,s2=0,s3=0;
        float a0=tb,a1=tb,a2=tb,a3=tb;       // theta: bias-first like before
        #pragma unroll 8
        for (int c = 0; c < 64; ++c) {
            float2 xa = *(const float2*)(xb + c*4096);
            float2 xc = *(const float2*)(xb + c*4096 + 64);
            float2 w  = wrow[c];             // {phi_w, psi_w}
            float st  = sth[c];              // broadcast read
            p0 += xa.x*w.x; p1 += xa.y*w.x; p2 += xc.x*w.x; p3 += xc.y*w.x;
            s0 += xa.x*w.y; s1 += xa.y*w.y; s2 += xc.x*w.y; s3 += xc.y*w.y;
            a0 += xa.x*st;  a1 += xa.y*st;  a2 += xc.x*st;  a3 += xc.y*st;
        }
        float pv = fmaxf(fmaxf(p0,p1), fmaxf(p2,p3)) + phi_b[i];
        float sv = fmaxf(fmaxf(s0,s1), fmaxf(s2,s3)) + psi_b[i];
        spsi[mIdx*33 + i] = sv;
        float v = pv * cp_w[32 + i];
        v += __shfl_xor(v, 16, 32);
        v += __shfl_xor(v,  8, 32);
        v += __shfl_xor(v,  4, 32);
        v += __shfl_xor(v,  2, 32);
        v += __shfl_xor(v,  1, 32);
        if (i == 0) {
            ws[OFF_BB + (b<<10) + m] = v;
            int nb = (b<<12) + ph*128 + pw*2;   // pixel (2ph,2pw)
            ws[OFF_A + nb]      = a0;
            ws[OFF_A + nb + 1]  = a1;
            ws[OFF_A + nb + 64] = a2;
            ws[OFF_A + nb + 65] = a3;
        }
        __syncthreads();
        #pragma unroll
        for (int rep = 0; rep < 2; ++rep) {
            int idx = tid + (rep << 10);     // 2048 outputs = 32 m x 64 o
            int ml = idx >> 6, o = idx & 63;
            const float* pr = &spsi[ml*33];  // wave-uniform ml: broadcast
            const float* wr = &sWw[o*33];    // (o+i)%32: 2-way max (free)
            float u = 0;
            #pragma unroll
            for (int i2 = 0; i2 < 32; ++i2) u += pr[i2]*wr[i2];
            ws[OFF_U + (((b<<10) + (sub<<5) + ml) << 6) + o] = u;
        }
    }
    gbar(ws, 1);

    // ---------- Phase 2: rank bb, k_n per pixel, per-b histogram ----------
    {
        float* sb = sh;
        sb[tid] = ws[OFF_BB + (b<<10) + tid];
        __syncthreads();
        {   // rank 32 m's of this chunk (32 lanes per m, integer-exact)
            int ml = tid >> 5, jl = tid & 31;
            int m = (sub << 5) + ml;
            float vv = sb[m];
            int cnt = 0;
            for (int s = 0; s < 32; ++s) {
                int j = jl + (s << 5);
                float u = sb[j];
                cnt += (u > vv || (u == vv && j < m)) ? 1 : 0;
            }
            cnt += __shfl_xor(cnt,  1, 32);
            cnt += __shfl_xor(cnt,  2, 32);
            cnt += __shfl_xor(cnt,  4, 32);
            cnt += __shfl_xor(cnt,  8, 32);
            cnt += __shfl_xor(cnt, 16, 32);
            if (jl == 0) {
                ws[OFF_SBB + (b<<10) + cnt] = vv;
                ((int*)ws)[OFF_PERM + (b<<10) + cnt] = m;
            }
        }
        {   // k_n for 128 pixels (8 lanes per pixel) + hist atomics
            int l = tid >> 3, jl = tid & 7;
            int n = (sub << 7) + l;
            float av = ws[OFF_A + (b<<12) + n];
            float tt = -av;
            const float2* sb2 = (const float2*)sb;
            int cnt = 0;
            for (int s = 0; s < 64; ++s) {
                float2 u = sb2[jl + (s << 3)];  // 8 distinct addrs: free
                cnt += (u.x > tt) ? 1 : 0;
                cnt += (u.y > tt) ? 1 : 0;
            }
            cnt += __shfl_xor(cnt, 1, 8);
            cnt += __shfl_xor(cnt, 2, 8);
            cnt += __shfl_xor(cnt, 4, 8);
            if (jl == 0) {
                ((int*)ws)[OFF_KK + (b<<12) + n] = cnt;
                atomicAdd(&ws[OFF_HC + b*1025 + cnt], 1.0f);
                atomicAdd(&ws[OFF_HS + b*1025 + cnt], av);
                atomicAdd(&ws[OFF_HS2 + b*1025 + cnt], av*av);
            }
        }
    }
    gbar(ws, 2);

    // ---------- Phase 3: sorted prefixes T1/T2 + BN moment partials ------
    // Exact kPS structure (bitwise-identical T1/T2); blocks 0..63 active.
    if (bid < 64) {
        int b3 = bid >> 3, og = bid & 7;
        int obase = og << 3;
        float* ssort = sh;
        int*   sperm = (int*)(sh + 1024);
        float* shc   = sh + 2048;
        float* shs   = sh + 3076;
        float* shs2  = sh + 4104;
        float* swp1  = sh + 5132;
        float* swp2  = sh + 5260;
        ssort[tid] = ws[OFF_SBB + (b3<<10) + tid];
        sperm[tid] = ((const int*)ws)[OFF_PERM + (b3<<10) + tid];
        shc[tid]  = ws[OFF_HC  + b3*1025 + tid];
        shs[tid]  = ws[OFF_HS  + b3*1025 + tid];
        shs2[tid] = ws[OFF_HS2 + b3*1025 + tid];
        if (tid == 0) {
            shc[1024]  = ws[OFF_HC  + b3*1025 + 1024];
            shs[1024]  = ws[OFF_HS  + b3*1025 + 1024];
            shs2[1024] = ws[OFF_HS2 + b3*1025 + 1024];
        }
        __syncthreads();
        int ch = tid >> 3, o = tid & 7;
        int wv = tid >> 6, chl = (tid & 63) >> 3;   // ch = wv*8 + chl
        const float* Ub = ws + OFF_U + (b3<<16) + obase + o;
        float p[8], sp[8];
        float s1 = 0, s2 = 0;
        #pragma unroll
        for (int jl = 0; jl < 8; ++jl) {
            int jj = (ch<<3) + jl;
            float v = Ub[sperm[jj]<<6];
            p[jl] = v;
            sp[jl] = ssort[jj]*v;
            s1 += v; s2 += sp[jl];
        }
        float own1 = s1, own2 = s2;
        #pragma unroll
        for (int d = 1; d < 8; d <<= 1) {
            float u1 = __shfl_up(s1, d<<3, 64);
            float u2 = __shfl_up(s2, d<<3, 64);
            if (chl >= d) { s1 += u1; s2 += u2; }
        }
        if (chl == 7) { swp1[(wv<<3)+o] = s1; swp2[(wv<<3)+o] = s2; }
        __syncthreads();
        float off1 = 0, off2 = 0;
        for (int w = 0; w < 16; ++w) {
            if (w < wv) { off1 += swp1[(w<<3)+o]; off2 += swp2[(w<<3)+o]; }
        }
        float run1 = off1 + s1 - own1;   // exclusive prefix before chunk ch
        float run2 = off2 + s2 - own2;
        float* T1 = ws + OFF_T1 + b3*65600 + obase + o;
        float* T2 = ws + OFF_T2 + b3*65600 + obase + o;
        if (ch == 0) { T1[0] = 0.0f; T2[0] = 0.0f; }   // k=0 row
        const float inv = 1.0f/1024.0f;
        float m1 = 0, m2 = 0;
        #pragma unroll
        for (int jl = 0; jl < 8; ++jl) {
            int k = (ch<<3) + jl + 1;
            run1 += p[jl]; run2 += sp[jl];
            float t1 = run1*inv, t2 = run2*inv;
            T1[k<<6] = t1;
            T2[k<<6] = t2;
            float c = shc[k], sa_ = shs[k], sa2 = shs2[k];
            m1 += sa_*t1 + c*t2;
            m2 += (sa2*t1 + 2.0f*sa_*t2)*t1 + c*t2*t2;
        }
        m1 += __shfl_xor(m1,  8, 64); m2 += __shfl_xor(m2,  8, 64);
        m1 += __shfl_xor(m1, 16, 64); m2 += __shfl_xor(m2, 16, 64);
        m1 += __shfl_xor(m1, 32, 64); m2 += __shfl_xor(m2, 32, 64);
        __syncthreads();   // swp reuse
        if (chl == 0) { swp1[(wv<<3)+o] = m1; swp2[(wv<<3)+o] = m2; }
        __syncthreads();
        if (tid < 8) {
            float a1 = 0, a2 = 0;
            for (int w = 0; w < 16; ++w) {
                a1 += swp1[(w<<3)+tid]; a2 += swp2[(w<<3)+tid];
            }
            // plain writes (no same-line atomics); P4 reduces over b3
            ws[OFF_MP1 + (b3<<6) + obase + tid] = a1;
            ws[OFF_MP2 + (b3<<6) + obase + tid] = a2;
        }
    }
    gbar(ws, 3);

    // ---------- Phase 4: output tile (128 pixels per block) --------------
    {
        float* tile = sh;               // 64 o x 129 (pad)
        float* sa = sh + 8256;          // a for 128 pixels
        int*   sk = (int*)(sh + 8384);  // k for 128 pixels
        float* sA = sh + 8512;
        float* sD = sh + 8576;
        int n0 = sub << 7;
        if (tid < 128) {
            sa[tid] = ws[OFF_A + (b<<12) + n0 + tid];
            sk[tid] = ((const int*)ws)[OFF_KK + (b<<12) + n0 + tid];
        }
        if (tid < 64) {
            const float Ninv = 1.0f/32768.0f;
            float m1s = 0, m2s = 0;
            #pragma unroll
            for (int b3 = 0; b3 < 8; ++b3) {
                m1s += ws[OFF_MP1 + (b3<<6) + tid];
                m2s += ws[OFF_MP2 + (b3<<6) + tid];
            }
            float m1 = m1s * Ninv;
            float m2 = m2s * Ninv;
            float wb = Wb[tid];
            float mu  = m1 + wb;
            float E2  = m2 + 2.0f*wb*m1 + wb*wb;
            float var = E2 - mu*mu;
            float A = gamma[tid] * rsqrtf(var + 1e-5f);
            sA[tid] = A;
            sD[tid] = beta[tid] + A*(wb - mu);
        }
        __syncthreads();
        const float* T1 = ws + OFF_T1 + b*65600;
        const float* T2 = ws + OFF_T2 + b*65600;
        {
            int o = tid & 63, ng = tid >> 6;   // 16 groups x 8 n
            float Ao = sA[o], Do = sD[o];
            #pragma unroll
            for (int j = 0; j < 8; ++j) {
                int n = (ng << 3) + j;
                int k = sk[n];                 // wave-uniform -> T coalesced
                float a = sa[n];
                float t1 = T1[(k<<6) + o];
                float t2 = T2[(k<<6) + o];
                tile[o*129 + n] = Ao*(a*t1 + t2) + Do;
            }
        }
        __syncthreads();
        {
            int n = tid & 127, og = tid >> 7;  // 8 groups x 8 o
            #pragma unroll
            for (int j = 0; j < 8; ++j) {
                int o = (og << 3) + j;
                int idx = ((b<<6) + o)*4096 + n0 + n;
                out[idx] = tile[o*129 + n] + x[idx];
            }
        }
    }
}

extern "C" void kernel_launch(void* const* d_in, const int* in_sizes, int n_in,
                              void* d_out, int out_size, void* d_ws, size_t ws_size,
                              hipStream_t stream)
{
    const float* x       = (const float*)d_in[0];
    const float* theta_w = (const float*)d_in[1];
    const float* theta_b = (const float*)d_in[2];
    const float* phi_w   = (const float*)d_in[3];
    const float* phi_b   = (const float*)d_in[4];
    const float* psi_w   = (const float*)d_in[5];
    const float* psi_b   = (const float*)d_in[6];
    const float* cp_w    = (const float*)d_in[7];
    const float* Ww      = (const float*)d_in[8];
    const float* Wb      = (const float*)d_in[9];
    const float* gamma   = (const float*)d_in[10];
    const float* beta    = (const float*)d_in[11];
    float* ws  = (float*)d_ws;
    float* out = (float*)d_out;

    // Zero hist + barrier counters in one contiguous memset:
    // floats [OFF_HC, OFF_BAR + 288) = 24888 floats = 99552 bytes.
    hipMemsetAsync(ws + OFF_HC, 0, 24888 * sizeof(float), stream);

    kMega<<<256, 1024, 0, stream>>>(x, theta_w, theta_b, phi_w, phi_b,
                                    psi_w, psi_b, cp_w, Ww, Wb,
                                    gamma, beta, ws, out);
}

// Round 4
// 132.562 us; speedup vs baseline: 1.6934x; 1.2763x over previous
//
#include <hip/hip_runtime.h>

// B=8, C=64, H=W=64, CI=32, N=4096 pixels, M=1024 pooled.
// y[b,n,:] = (a_n*S1[k_n,:] + S2[k_n,:])/1024 ; only W_w . y is needed, so
// track U = Ww.psi (64-dim) and its sorted-order prefixes T1/T2 directly.
// BN stats from per-k scalars (cnt, sum a, sum a^2) x T rows - no Gram.
//
// r9: fence-free grid sync. r8 proved arrival-count is not the barrier
// cost (tree==flat); the shared cost is the agent fence pair
// (buffer_wbl2/buffer_inv = full per-XCD L2 writeback+invalidate, 256
// blocks x 3 barriers). Fix: ALL cross-block data moves via
// __hip_atomic_{load,store}(RELAXED, AGENT) -> sc1 ops that bypass the
// non-coherent L2 and live at the coherence point. Then the barrier is
// just: __syncthreads (drains vmcnt per wave = release for sc1 stores,
// per LLVM gfx94x memory model) + relaxed RMW arrival + sc1 poll. No
// wbl2, no inv. Residency: 32 blocks/CU-class unchanged (<=40 VGPR,
// 34.8KB LDS, 256 blocks on 256 CUs).
#define OFF_A    0         // a[b][n]               : 32768 floats
#define OFF_BB   32768     // bb[b][m]              : 8192
#define OFF_SBB  40960     // sorted-desc bb[b][k]  : 8192
#define OFF_PERM 49152     // perm[b][k] (int)      : 8192
#define OFF_U    57344     // U[b][m][o]            : 8*1024*64 = 524288
#define OFF_T1   581632    // T1[b][k<=1024][o]     : 8*1025*64 = 524800
#define OFF_T2   1106432   // T2[b][k][o]           : 524800
#define OFF_KK   1631232   // k[b][n] (int)         : 32768
#define OFF_MP1  1664000   // moment1 partials [b3][o] : 512
#define OFF_MP2  1664512   // moment2 partials [b3][o] : 512
#define OFF_HC   1665024   // hist cnt[b][1025]     : 8200
#define OFF_HS   1673224   // hist sum_a[b][1025]   : 8200
#define OFF_HS2  1681424   // hist sum_a2[b][1025]  : 8200
#define OFF_BAR  1689624   // root ctr @+0; group g ctr @+32*(g+1); 288 u32
// memset zeroes floats [OFF_HC, OFF_BAR+288) = 24888 floats = 99552 bytes

#define NBLK 256
#define NGRP 8

// Coherent (sc1, L2-bypass) scalar access helpers for cross-block data.
__device__ __forceinline__ void stg(float* p, float v) {
    __hip_atomic_store(p, v, __ATOMIC_RELAXED, __HIP_MEMORY_SCOPE_AGENT);
}
__device__ __forceinline__ float ldg1(const float* p) {
    return __hip_atomic_load(p, __ATOMIC_RELAXED, __HIP_MEMORY_SCOPE_AGENT);
}
__device__ __forceinline__ void stgi(int* p, int v) {
    __hip_atomic_store(p, v, __ATOMIC_RELAXED, __HIP_MEMORY_SCOPE_AGENT);
}
__device__ __forceinline__ int ldgi(const int* p) {
    return __hip_atomic_load(p, __ATOMIC_RELAXED, __HIP_MEMORY_SCOPE_AGENT);
}

// Fence-free two-level monotonic grid barrier. The preceding
// __syncthreads() drains every wave's vmcnt (release for the sc1 data
// stores); arrival/poll are relaxed agent atomics (sc1, no L2 flush).
__device__ __forceinline__ void gbar(float* ws, int gen)
{
    __syncthreads();
    if (threadIdx.x == 0) {
        unsigned* bars = (unsigned*)(ws + OFF_BAR);
        unsigned* grp  = bars + ((blockIdx.x >> 5) + 1) * 32;
        unsigned old = __hip_atomic_fetch_add(grp, 1u, __ATOMIC_RELAXED,
                                              __HIP_MEMORY_SCOPE_AGENT);
        if (old == (unsigned)(gen * 32 - 1))     // last of this 32-group
            __hip_atomic_fetch_add(bars, 1u, __ATOMIC_RELAXED,
                                   __HIP_MEMORY_SCOPE_AGENT);
        unsigned goal = (unsigned)(gen * NGRP);
        while (__hip_atomic_load(bars, __ATOMIC_RELAXED,
                                 __HIP_MEMORY_SCOPE_AGENT) < goal)
            __builtin_amdgcn_s_sleep(2);
    }
    __syncthreads();
}

// LDS carve (floats), phases reuse one 8640-float block (34.6 KB):
// P1: sm[0..4160) sth[4160..4228) spsi[4228..5284) sWw[5284..7396)
// P2: sb[0..1024)
// P3: ssort[0..1024) sperm[1024..2048) shc[2048..3076) shs[3076..4104)
//     shs2[4104..5132) swp1[5132..5260) swp2[5260..5388)
// P4: tile[0..8256)=64x129 sa[8256..8384) sk[8384..8512) sA[8512..8576)
//     sD[8576..8640)
__global__ __launch_bounds__(1024) void kMega(
    const float* __restrict__ x, const float* __restrict__ theta_w,
    const float* __restrict__ theta_b, const float* __restrict__ phi_w,
    const float* __restrict__ phi_b, const float* __restrict__ psi_w,
    const float* __restrict__ psi_b, const float* __restrict__ cp_w,
    const float* __restrict__ Ww, const float* __restrict__ Wb,
    const float* __restrict__ gamma, const float* __restrict__ beta,
    float* __restrict__ ws, float* __restrict__ out)
{
    __shared__ float sh[8640];
    const int tid = threadIdx.x;
    const int bid = blockIdx.x;
    const int b   = bid >> 5;     // 32 blocks per batch image
    const int sub = bid & 31;

    // ---------- Phase 1: phi/psi conv+pool -> bb, U ; theta -> a ----------
    {
        float* sm   = sh;          // 32 i-rows x 130: interleaved {phi,psi}
        float* sth  = sh + 4160;   // tw_eff[64] + tb_eff
        float* spsi = sh + 4228;   // 32 m-rows x 32 i (pad 33)
        float* sWw  = sh + 5284;   // 64 o-rows x 32 i (pad 33)
        for (int e = tid; e < 2048; e += 1024) {
            int i = e >> 6, c = e & 63;
            sm[i*130 + 2*c]     = phi_w[e];
            sm[i*130 + 2*c + 1] = psi_w[e];
        }
        for (int e = tid; e < 2048; e += 1024)
            sWw[(e >> 5)*33 + (e & 31)] = Ww[(e >> 5)*33 + (e & 31)];
        if (tid < 64) {
            float s = 0;
            for (int i = 0; i < 32; ++i) s += cp_w[i]*theta_w[i*64 + tid];
            sth[tid] = s;
        } else if (tid == 64) {
            float s = 0;
            for (int i = 0; i < 32; ++i) s += cp_w[i]*theta_b[i];
            sth[64] = s;
        }
        __syncthreads();
        int i = tid & 31;
        int mIdx = tid >> 5;                 // 0..31
        int m = (sub << 5) + mIdx;
        int ph = m >> 5, pw = m & 31;
        const float* xb = x + b*262144 + ph*128 + pw*2;
        const float2* wrow = (const float2*)(sm + i*130);
        float tb = sth[64];
        float p0=0,p1=0,p2=0,p3=0,s0=0,s1=0,s2=0,s3=0;
        float a0=tb,a1=tb,a2=tb,a3=tb;       // theta: bias-first like before
        #pragma unroll 8
        for (int c = 0; c < 64; ++c) {
            float2 xa = *(const float2*)(xb + c*4096);
            float2 xc = *(const float2*)(xb + c*4096 + 64);
            float2 w  = wrow[c];             // {phi_w, psi_w}
            float st  = sth[c];              // broadcast read
            p0 += xa.x*w.x; p1 += xa.y*w.x; p2 += xc.x*w.x; p3 += xc.y*w.x;
            s0 += xa.x*w.y; s1 += xa.y*w.y; s2 += xc.x*w.y; s3 += xc.y*w.y;
            a0 += xa.x*st;  a1 += xa.y*st;  a2 += xc.x*st;  a3 += xc.y*st;
        }
        float pv = fmaxf(fmaxf(p0,p1), fmaxf(p2,p3)) + phi_b[i];
        float sv = fmaxf(fmaxf(s0,s1), fmaxf(s2,s3)) + psi_b[i];
        spsi[mIdx*33 + i] = sv;
        float v = pv * cp_w[32 + i];
        v += __shfl_xor(v, 16, 32);
        v += __shfl_xor(v,  8, 32);
        v += __shfl_xor(v,  4, 32);
        v += __shfl_xor(v,  2, 32);
        v += __shfl_xor(v,  1, 32);
        if (i == 0) {
            stg(&ws[OFF_BB + (b<<10) + m], v);
            int nb = (b<<12) + ph*128 + pw*2;   // pixel (2ph,2pw)
            stg(&ws[OFF_A + nb],      a0);
            stg(&ws[OFF_A + nb + 1],  a1);
            stg(&ws[OFF_A + nb + 64], a2);
            stg(&ws[OFF_A + nb + 65], a3);
        }
        __syncthreads();
        #pragma unroll
        for (int rep = 0; rep < 2; ++rep) {
            int idx = tid + (rep << 10);     // 2048 outputs = 32 m x 64 o
            int ml = idx >> 6, o = idx & 63;
            const float* pr = &spsi[ml*33];  // wave-uniform ml: broadcast
            const float* wr = &sWw[o*33];    // (o+i)%32: 2-way max (free)
            float u = 0;
            #pragma unroll
            for (int i2 = 0; i2 < 32; ++i2) u += pr[i2]*wr[i2];
            stg(&ws[OFF_U + (((b<<10) + (sub<<5) + ml) << 6) + o], u);
        }
    }
    gbar(ws, 1);

    // ---------- Phase 2: rank bb, k_n per pixel, per-b histogram ----------
    {
        float* sb = sh;
        sb[tid] = ldg1(&ws[OFF_BB + (b<<10) + tid]);
        __syncthreads();
        {   // rank 32 m's of this chunk (32 lanes per m, integer-exact)
            int ml = tid >> 5, jl = tid & 31;
            int m = (sub << 5) + ml;
            float vv = sb[m];
            int cnt = 0;
            for (int s = 0; s < 32; ++s) {
                int j = jl + (s << 5);
                float u = sb[j];
                cnt += (u > vv || (u == vv && j < m)) ? 1 : 0;
            }
            cnt += __shfl_xor(cnt,  1, 32);
            cnt += __shfl_xor(cnt,  2, 32);
            cnt += __shfl_xor(cnt,  4, 32);
            cnt += __shfl_xor(cnt,  8, 32);
            cnt += __shfl_xor(cnt, 16, 32);
            if (jl == 0) {
                stg(&ws[OFF_SBB + (b<<10) + cnt], vv);
                stgi(&((int*)ws)[OFF_PERM + (b<<10) + cnt], m);
            }
        }
        {   // k_n for 128 pixels (8 lanes per pixel) + hist atomics
            int l = tid >> 3, jl = tid & 7;
            int n = (sub << 7) + l;
            float av = ldg1(&ws[OFF_A + (b<<12) + n]);
            float tt = -av;
            const float2* sb2 = (const float2*)sb;
            int cnt = 0;
            for (int s = 0; s < 64; ++s) {
                float2 u = sb2[jl + (s << 3)];  // 8 distinct addrs: free
                cnt += (u.x > tt) ? 1 : 0;
                cnt += (u.y > tt) ? 1 : 0;
            }
            cnt += __shfl_xor(cnt, 1, 8);
            cnt += __shfl_xor(cnt, 2, 8);
            cnt += __shfl_xor(cnt, 4, 8);
            if (jl == 0) {
                stgi(&((int*)ws)[OFF_KK + (b<<12) + n], cnt);
                atomicAdd(&ws[OFF_HC + b*1025 + cnt], 1.0f);
                atomicAdd(&ws[OFF_HS + b*1025 + cnt], av);
                atomicAdd(&ws[OFF_HS2 + b*1025 + cnt], av*av);
            }
        }
    }
    gbar(ws, 2);

    // ---------- Phase 3: sorted prefixes T1/T2 + BN moment partials ------
    // Exact kPS structure (bitwise-identical T1/T2); blocks 0..63 active.
    if (bid < 64) {
        int b3 = bid >> 3, og = bid & 7;
        int obase = og << 3;
        float* ssort = sh;
        int*   sperm = (int*)(sh + 1024);
        float* shc   = sh + 2048;
        float* shs   = sh + 3076;
        float* shs2  = sh + 4104;
        float* swp1  = sh + 5132;
        float* swp2  = sh + 5260;
        ssort[tid] = ldg1(&ws[OFF_SBB + (b3<<10) + tid]);
        sperm[tid] = ldgi(&((const int*)ws)[OFF_PERM + (b3<<10) + tid]);
        shc[tid]  = ldg1(&ws[OFF_HC  + b3*1025 + tid]);
        shs[tid]  = ldg1(&ws[OFF_HS  + b3*1025 + tid]);
        shs2[tid] = ldg1(&ws[OFF_HS2 + b3*1025 + tid]);
        if (tid == 0) {
            shc[1024]  = ldg1(&ws[OFF_HC  + b3*1025 + 1024]);
            shs[1024]  = ldg1(&ws[OFF_HS  + b3*1025 + 1024]);
            shs2[1024] = ldg1(&ws[OFF_HS2 + b3*1025 + 1024]);
        }
        __syncthreads();
        int ch = tid >> 3, o = tid & 7;
        int wv = tid >> 6, chl = (tid & 63) >> 3;   // ch = wv*8 + chl
        const float* Ub = ws + OFF_U + (b3<<16) + obase + o;
        float p[8], sp[8];
        float s1 = 0, s2 = 0;
        #pragma unroll
        for (int jl = 0; jl < 8; ++jl) {
            int jj = (ch<<3) + jl;
            float v = ldg1(&Ub[sperm[jj]<<6]);
            p[jl] = v;
            sp[jl] = ssort[jj]*v;
            s1 += v; s2 += sp[jl];
        }
        float own1 = s1, own2 = s2;
        #pragma unroll
        for (int d = 1; d < 8; d <<= 1) {
            float u1 = __shfl_up(s1, d<<3, 64);
            float u2 = __shfl_up(s2, d<<3, 64);
            if (chl >= d) { s1 += u1; s2 += u2; }
        }
        if (chl == 7) { swp1[(wv<<3)+o] = s1; swp2[(wv<<3)+o] = s2; }
        __syncthreads();
        float off1 = 0, off2 = 0;
        for (int w = 0; w < 16; ++w) {
            if (w < wv) { off1 += swp1[(w<<3)+o]; off2 += swp2[(w<<3)+o]; }
        }
        float run1 = off1 + s1 - own1;   // exclusive prefix before chunk ch
        float run2 = off2 + s2 - own2;
        float* T1 = ws + OFF_T1 + b3*65600 + obase + o;
        float* T2 = ws + OFF_T2 + b3*65600 + obase + o;
        if (ch == 0) { stg(&T1[0], 0.0f); stg(&T2[0], 0.0f); }  // k=0 row
        const float inv = 1.0f/1024.0f;
        float m1 = 0, m2 = 0;
        #pragma unroll
        for (int jl = 0; jl < 8; ++jl) {
            int k = (ch<<3) + jl + 1;
            run1 += p[jl]; run2 += sp[jl];
            float t1 = run1*inv, t2 = run2*inv;
            stg(&T1[k<<6], t1);
            stg(&T2[k<<6], t2);
            float c = shc[k], sa_ = shs[k], sa2 = shs2[k];
            m1 += sa_*t1 + c*t2;
            m2 += (sa2*t1 + 2.0f*sa_*t2)*t1 + c*t2*t2;
        }
        m1 += __shfl_xor(m1,  8, 64); m2 += __shfl_xor(m2,  8, 64);
        m1 += __shfl_xor(m1, 16, 64); m2 += __shfl_xor(m2, 16, 64);
        m1 += __shfl_xor(m1, 32, 64); m2 += __shfl_xor(m2, 32, 64);
        __syncthreads();   // swp reuse
        if (chl == 0) { swp1[(wv<<3)+o] = m1; swp2[(wv<<3)+o] = m2; }
        __syncthreads();
        if (tid < 8) {
            float a1 = 0, a2 = 0;
            for (int w = 0; w < 16; ++w) {
                a1 += swp1[(w<<3)+tid]; a2 += swp2[(w<<3)+tid];
            }
            // plain coherent writes; P4 reduces over b3
            stg(&ws[OFF_MP1 + (b3<<6) + obase + tid], a1);
            stg(&ws[OFF_MP2 + (b3<<6) + obase + tid], a2);
        }
    }
    gbar(ws, 3);

    // ---------- Phase 4: output tile (128 pixels per block) --------------
    {
        float* tile = sh;               // 64 o x 129 (pad)
        float* sa = sh + 8256;          // a for 128 pixels
        int*   sk = (int*)(sh + 8384);  // k for 128 pixels
        float* sA = sh + 8512;
        float* sD = sh + 8576;
        int n0 = sub << 7;
        if (tid < 128) {
            sa[tid] = ldg1(&ws[OFF_A + (b<<12) + n0 + tid]);
            sk[tid] = ldgi(&((const int*)ws)[OFF_KK + (b<<12) + n0 + tid]);
        }
        if (tid < 64) {
            const float Ninv = 1.0f/32768.0f;
            float m1s = 0, m2s = 0;
            #pragma unroll
            for (int b3 = 0; b3 < 8; ++b3) {
                m1s += ldg1(&ws[OFF_MP1 + (b3<<6) + tid]);
                m2s += ldg1(&ws[OFF_MP2 + (b3<<6) + tid]);
            }
            float m1 = m1s * Ninv;
            float m2 = m2s * Ninv;
            float wb = Wb[tid];
            float mu  = m1 + wb;
            float E2  = m2 + 2.0f*wb*m1 + wb*wb;
            float var = E2 - mu*mu;
            float A = gamma[tid] * rsqrtf(var + 1e-5f);
            sA[tid] = A;
            sD[tid] = beta[tid] + A*(wb - mu);
        }
        __syncthreads();
        const float* T1 = ws + OFF_T1 + b*65600;
        const float* T2 = ws + OFF_T2 + b*65600;
        {
            int o = tid & 63, ng = tid >> 6;   // 16 groups x 8 n
            float Ao = sA[o], Do = sD[o];
            #pragma unroll
            for (int j = 0; j < 8; ++j) {
                int n = (ng << 3) + j;
                int k = sk[n];                 // wave-uniform -> T coalesced
                float a = sa[n];
                float t1 = ldg1(&T1[(k<<6) + o]);
                float t2 = ldg1(&T2[(k<<6) + o]);
                tile[o*129 + n] = Ao*(a*t1 + t2) + Do;
            }
        }
        __syncthreads();
        {
            int n = tid & 127, og = tid >> 7;  // 8 groups x 8 o
            #pragma unroll
            for (int j = 0; j < 8; ++j) {
                int o = (og << 3) + j;
                int idx = ((b<<6) + o)*4096 + n0 + n;
                out[idx] = tile[o*129 + n] + x[idx];
            }
        }
    }
}

extern "C" void kernel_launch(void* const* d_in, const int* in_sizes, int n_in,
                              void* d_out, int out_size, void* d_ws, size_t ws_size,
                              hipStream_t stream)
{
    const float* x       = (const float*)d_in[0];
    const float* theta_w = (const float*)d_in[1];
    const float* theta_b = (const float*)d_in[2];
    const float* phi_w   = (const float*)d_in[3];
    const float* phi_b   = (const float*)d_in[4];
    const float* psi_w   = (const float*)d_in[5];
    const float* psi_b   = (const float*)d_in[6];
    const float* cp_w    = (const float*)d_in[7];
    const float* Ww      = (const float*)d_in[8];
    const float* Wb      = (const float*)d_in[9];
    const float* gamma   = (const float*)d_in[10];
    const float* beta    = (const float*)d_in[11];
    float* ws  = (float*)d_ws;
    float* out = (float*)d_out;

    // Zero hist + barrier counters in one contiguous memset:
    // floats [OFF_HC, OFF_BAR + 288) = 24888 floats = 99552 bytes.
    hipMemsetAsync(ws + OFF_HC, 0, 24888 * sizeof(float), stream);

    kMega<<<256, 1024, 0, stream>>>(x, theta_w, theta_b, phi_w, phi_b,
                                    psi_w, psi_b, cp_w, Ww, Wb,
                                    gamma, beta, ws, out);
}